// Round 2
// baseline (587.071 us; speedup 1.0000x reference)
//
#include <hip/hip_runtime.h>

typedef __bf16 bf16x8 __attribute__((ext_vector_type(8)));
typedef float f32x4 __attribute__((ext_vector_type(4)));
typedef unsigned short u16;
typedef u16 u16x8 __attribute__((ext_vector_type(8)));
typedef u16 u16x4 __attribute__((ext_vector_type(4)));

#define DEVI static __device__ __forceinline__

// fp32 -> bf16 round-to-nearest-even (bit pattern)
DEVI u16 f2bf(float f) {
  unsigned u = __float_as_uint(f);
  u += 0x7FFFu + ((u >> 16) & 1u);
  return (u16)(u >> 16);
}

DEVI void gload_lds16(const void* g, void* l) {
  __builtin_amdgcn_global_load_lds((const __attribute__((address_space(1))) void*)g,
                                   (__attribute__((address_space(3))) void*)l, 16, 0, 0);
}

// ---------------------------------------------------------------------------
// Transpose fp32 [R][C] -> bf16 [C][R].  Tile 64x64, grid (C/64, R/64).
// ---------------------------------------------------------------------------
__global__ __launch_bounds__(256) void k_transpose_w(const float* __restrict__ in,
                                                     u16* __restrict__ out, int R, int C) {
  __shared__ float tile[64][65];
  const int t = threadIdx.x;
  const int c0 = blockIdx.x * 64, r0 = blockIdx.y * 64;
#pragma unroll
  for (int i = 0; i < 4; ++i) {
    int id = t + i * 256;            // 0..1023 : 64 rows x 16 float4
    int r = id >> 4, c4 = (id & 15) * 4;
    f32x4 v = *(const f32x4*)(in + (size_t)(r0 + r) * C + c0 + c4);
#pragma unroll
    for (int j = 0; j < 4; ++j) tile[r][c4 + j] = v[j];
  }
  __syncthreads();
  const int oc = t >> 2;             // 0..63 : output row (= input col)
  const int rr = (t & 3) * 16;
  u16x8 lo, hi;
#pragma unroll
  for (int j = 0; j < 8; ++j) lo[j] = f2bf(tile[rr + j][oc]);
#pragma unroll
  for (int j = 0; j < 8; ++j) hi[j] = f2bf(tile[rr + 8 + j][oc]);
  u16* dst = out + (size_t)(c0 + oc) * R + r0 + rr;
  *(u16x8*)dst = lo;
  *(u16x8*)(dst + 8) = hi;
}

// ---------------------------------------------------------------------------
// Transpose V slice of qkv (bf16) into vT[B*H][64][2048].  grid (S/64, B*H)
// ---------------------------------------------------------------------------
__global__ __launch_bounds__(256) void k_transpose_v(const u16* __restrict__ qkv,
                                                     u16* __restrict__ vt) {
  __shared__ u16 tile[64][72];
  const int t = threadIdx.x;
  const int bh = blockIdx.y;                 // b*12+h
  const int b = bh / 12, h = bh % 12;
  const int s0 = blockIdx.x * 64;
  const u16* src = qkv + (size_t)b * 2048 * 2304 + 1536 + h * 64;
#pragma unroll
  for (int i = 0; i < 2; ++i) {
    int id = t + i * 256;                    // 0..511 : 64 rows x 8 chunks
    int r = id >> 3, c8 = (id & 7) * 8;
    *(u16x8*)&tile[r][c8] = *(const u16x8*)(src + (size_t)(s0 + r) * 2304 + c8);
  }
  __syncthreads();
  const int od = t >> 2;                     // 0..63 (d)
  const int rr = (t & 3) * 16;
  u16x8 lo, hi;
#pragma unroll
  for (int j = 0; j < 8; ++j) lo[j] = tile[rr + j][od];
#pragma unroll
  for (int j = 0; j < 8; ++j) hi[j] = tile[rr + 8 + j][od];
  u16* dst = vt + ((size_t)bh * 64 + od) * 2048 + s0 + rr;
  *(u16x8*)dst = lo;
  *(u16x8*)(dst + 8) = hi;
}

// ---------------------------------------------------------------------------
// LayerNorm: fp32 [8192][768] -> bf16 [8192][768]. block 192 (1 float4/thread)
// ---------------------------------------------------------------------------
__global__ __launch_bounds__(192) void k_layernorm(const float* __restrict__ x,
                                                   const float* __restrict__ w,
                                                   const float* __restrict__ bvec,
                                                   u16* __restrict__ out) {
  const int row = blockIdx.x, t = threadIdx.x;
  const float* xr = x + (size_t)row * 768;
  f32x4 v = *(const f32x4*)(xr + t * 4);
  float s = v[0] + v[1] + v[2] + v[3];
  float sq = v[0] * v[0] + v[1] * v[1] + v[2] * v[2] + v[3] * v[3];
#pragma unroll
  for (int m = 1; m < 64; m <<= 1) { s += __shfl_xor(s, m); sq += __shfl_xor(sq, m); }
  __shared__ float red[2][3];
  const int wv = t >> 6;
  if ((t & 63) == 0) { red[0][wv] = s; red[1][wv] = sq; }
  __syncthreads();
  s = red[0][0] + red[0][1] + red[0][2];
  sq = red[1][0] + red[1][1] + red[1][2];
  const float mean = s * (1.0f / 768.0f);
  const float var = sq * (1.0f / 768.0f) - mean * mean;
  const float rstd = rsqrtf(var + 1e-5f);
  f32x4 wv4 = *(const f32x4*)(w + t * 4);
  f32x4 bv4 = *(const f32x4*)(bvec + t * 4);
  u16x4 o;
#pragma unroll
  for (int j = 0; j < 4; ++j) o[j] = f2bf((v[j] - mean) * rstd * wv4[j] + bv4[j]);
  *(u16x4*)(out + (size_t)row * 768 + t * 4) = o;
}

// ---------------------------------------------------------------------------
// GEMM: C[M][N] = A[M][K](bf16) * BT[N][K](bf16)^T + bias (+epilogue)
// 128x128 tile, BK=32, 4 waves, m97 structure w/ global_load_lds(16B).
// ---------------------------------------------------------------------------
#define EPI_QKV 0    // bf16 out = val
#define EPI_RESID 1  // f32  out = val + resid
#define EPI_GELU 2   // bf16 out = gelu(val)

template <int EPI>
__global__ __launch_bounds__(256) void k_gemm(const u16* __restrict__ A,
                                              const u16* __restrict__ BT,
                                              const float* __restrict__ bias,
                                              const float* __restrict__ resid,
                                              void* __restrict__ outp,
                                              int M, int N, int K) {
  __shared__ u16 As[128 * 32];
  __shared__ u16 Bs[128 * 32];
  const int t = threadIdx.x;
  const int lane = t & 63, w = t >> 6;
  const int l15 = lane & 15, l4 = lane >> 4;
  const int wr = w >> 1, wc = w & 1;
  const int m0 = blockIdx.y * 128, n0 = blockIdx.x * 128;

  f32x4 acc[4][4] = {};

  for (int kt = 0; kt < K; kt += 32) {
#pragma unroll
    for (int i = 0; i < 2; ++i) {
      int c = w * 128 + i * 64 + lane;       // 16B chunk id, 0..511
      int m = c >> 2, k16 = (c & 3) * 8;
      gload_lds16(A + (size_t)(m0 + m) * K + kt + k16, As + c * 8);
    }
#pragma unroll
    for (int i = 0; i < 2; ++i) {
      int c = w * 128 + i * 64 + lane;
      int n = c >> 2, k16 = (c & 3) * 8;
      gload_lds16(BT + (size_t)(n0 + n) * K + kt + k16, Bs + c * 8);
    }
    __syncthreads();
    bf16x8 af[4], bfr[4];
#pragma unroll
    for (int f = 0; f < 4; ++f)
      af[f] = *(const bf16x8*)(As + (wr * 64 + f * 16 + l15) * 32 + l4 * 8);
#pragma unroll
    for (int f = 0; f < 4; ++f)
      bfr[f] = *(const bf16x8*)(Bs + (wc * 64 + f * 16 + l15) * 32 + l4 * 8);
#pragma unroll
    for (int fi = 0; fi < 4; ++fi)
#pragma unroll
      for (int fj = 0; fj < 4; ++fj)
        acc[fi][fj] = __builtin_amdgcn_mfma_f32_16x16x32_bf16(af[fi], bfr[fj], acc[fi][fj], 0, 0, 0);
    __syncthreads();
  }

#pragma unroll
  for (int fi = 0; fi < 4; ++fi) {
    const int mbase = m0 + wr * 64 + fi * 16 + l4 * 4;
#pragma unroll
    for (int fj = 0; fj < 4; ++fj) {
      const int n = n0 + wc * 64 + fj * 16 + l15;
      const float bn = bias[n];
#pragma unroll
      for (int r = 0; r < 4; ++r) {
        const size_t idx = (size_t)(mbase + r) * N + n;
        float val = acc[fi][fj][r] + bn;
        if constexpr (EPI == EPI_QKV) {
          ((u16*)outp)[idx] = f2bf(val);
        } else if constexpr (EPI == EPI_RESID) {
          ((float*)outp)[idx] = val + resid[idx];
        } else {
          float g = 0.5f * val * (1.0f + tanhf(0.7978845608028654f * (val + 0.044715f * val * val * val)));
          ((u16*)outp)[idx] = f2bf(g);
        }
      }
    }
  }
}

// ---------------------------------------------------------------------------
// Causal flash attention.  grid (S/64, H, B), 256 thr (4 waves x 16 q-rows).
// qkv bf16 [B*S][2304]; vt bf16 [B*H][64][2048]; out bf16 [B*S][768].
// ---------------------------------------------------------------------------
__global__ __launch_bounds__(256) void k_attn(const u16* __restrict__ qkv,
                                              const u16* __restrict__ vt,
                                              u16* __restrict__ out) {
  __shared__ u16 Ks[64 * 72];
  __shared__ u16 Vs[64 * 72];
  __shared__ u16 Ps[4][16 * 72];
  const int t = threadIdx.x, lane = t & 63, w = t >> 6;
  const int l15 = lane & 15, l4 = lane >> 4;
  const int qt = blockIdx.x, h = blockIdx.y, b = blockIdx.z;
  const int q0 = qt * 64;
  const u16* qbase = qkv + (size_t)b * 2048 * 2304 + h * 64;
  const u16* kbase = qbase + 768;
  const u16* vtb = vt + ((size_t)(b * 12 + h) * 64) * 2048;

  const int qrow = q0 + w * 16 + l15;
  bf16x8 qf0 = *(const bf16x8*)(qbase + (size_t)qrow * 2304 + l4 * 8);
  bf16x8 qf1 = *(const bf16x8*)(qbase + (size_t)qrow * 2304 + 32 + l4 * 8);

  float m_run[4], l_run[4];
  f32x4 o_acc[4] = {};
#pragma unroll
  for (int r = 0; r < 4; ++r) { m_run[r] = -1e30f; l_run[r] = 0.f; }

  for (int kt = 0; kt <= qt; ++kt) {
    const int kv0 = kt * 64;
#pragma unroll
    for (int i = 0; i < 2; ++i) {
      int id = t + i * 256;
      int r = id >> 3, c8 = (id & 7) * 8;
      *(u16x8*)&Ks[r * 72 + c8] = *(const u16x8*)(kbase + (size_t)(kv0 + r) * 2304 + c8);
      *(u16x8*)&Vs[r * 72 + c8] = *(const u16x8*)(vtb + (size_t)r * 2048 + kv0 + c8);
    }
    __syncthreads();

    f32x4 sa[4] = {};
#pragma unroll
    for (int c = 0; c < 4; ++c) {
      bf16x8 kf0 = *(const bf16x8*)(Ks + (c * 16 + l15) * 72 + l4 * 8);
      bf16x8 kf1 = *(const bf16x8*)(Ks + (c * 16 + l15) * 72 + 32 + l4 * 8);
      sa[c] = __builtin_amdgcn_mfma_f32_16x16x32_bf16(qf0, kf0, sa[c], 0, 0, 0);
      sa[c] = __builtin_amdgcn_mfma_f32_16x16x32_bf16(qf1, kf1, sa[c], 0, 0, 0);
    }

    const int qrl = q0 + w * 16 + l4 * 4;
#pragma unroll
    for (int c = 0; c < 4; ++c)
#pragma unroll
      for (int r = 0; r < 4; ++r) {
        float s = sa[c][r] * 0.125f;
        if (kt == qt && (kv0 + c * 16 + l15) > (qrl + r)) s = -1e30f;
        sa[c][r] = s;
      }

    float pm[4];
#pragma unroll
    for (int r = 0; r < 4; ++r)
      pm[r] = fmaxf(fmaxf(sa[0][r], sa[1][r]), fmaxf(sa[2][r], sa[3][r]));
#pragma unroll
    for (int m = 1; m < 16; m <<= 1)
#pragma unroll
      for (int r = 0; r < 4; ++r) pm[r] = fmaxf(pm[r], __shfl_xor(pm[r], m));

    float sc[4];
#pragma unroll
    for (int r = 0; r < 4; ++r) {
      float mn = fmaxf(m_run[r], pm[r]);
      sc[r] = expf(m_run[r] - mn);
      m_run[r] = mn;
    }
    float ls[4] = {0.f, 0.f, 0.f, 0.f};
#pragma unroll
    for (int c = 0; c < 4; ++c)
#pragma unroll
      for (int r = 0; r < 4; ++r) {
        float p = expf(sa[c][r] - m_run[r]);
        sa[c][r] = p;
        ls[r] += p;
      }
#pragma unroll
    for (int m = 1; m < 16; m <<= 1)
#pragma unroll
      for (int r = 0; r < 4; ++r) ls[r] += __shfl_xor(ls[r], m);
#pragma unroll
    for (int r = 0; r < 4; ++r) l_run[r] = l_run[r] * sc[r] + ls[r];
#pragma unroll
    for (int c = 0; c < 4; ++c)
#pragma unroll
      for (int r = 0; r < 4; ++r) o_acc[c][r] *= sc[r];

    // P -> per-wave LDS bounce into MFMA A-layout
    u16* pw = &Ps[w][0];
#pragma unroll
    for (int c = 0; c < 4; ++c)
#pragma unroll
      for (int r = 0; r < 4; ++r)
        pw[(l4 * 4 + r) * 72 + c * 16 + l15] = f2bf(sa[c][r]);
    bf16x8 pa0 = *(const bf16x8*)(pw + l15 * 72 + l4 * 8);
    bf16x8 pa1 = *(const bf16x8*)(pw + l15 * 72 + 32 + l4 * 8);

#pragma unroll
    for (int c = 0; c < 4; ++c) {
      bf16x8 vf0 = *(const bf16x8*)(Vs + (c * 16 + l15) * 72 + l4 * 8);
      bf16x8 vf1 = *(const bf16x8*)(Vs + (c * 16 + l15) * 72 + 32 + l4 * 8);
      o_acc[c] = __builtin_amdgcn_mfma_f32_16x16x32_bf16(pa0, vf0, o_acc[c], 0, 0, 0);
      o_acc[c] = __builtin_amdgcn_mfma_f32_16x16x32_bf16(pa1, vf1, o_acc[c], 0, 0, 0);
    }
    __syncthreads();
  }

#pragma unroll
  for (int c = 0; c < 4; ++c)
#pragma unroll
    for (int r = 0; r < 4; ++r) {
      int qr = q0 + w * 16 + l4 * 4 + r;
      float o = o_acc[c][r] / l_run[r];
      out[((size_t)(b * 2048) + qr) * 768 + h * 64 + c * 16 + l15] = f2bf(o);
    }
}

// ---------------------------------------------------------------------------
extern "C" void kernel_launch(void* const* d_in, const int* in_sizes, int n_in,
                              void* d_out, int out_size, void* d_ws, size_t ws_size,
                              hipStream_t stream) {
  (void)in_sizes; (void)n_in; (void)out_size; (void)ws_size;
  const float* x      = (const float*)d_in[0];
  const float* ln1_w  = (const float*)d_in[1];
  const float* ln1_b  = (const float*)d_in[2];
  const float* w_attn = (const float*)d_in[3];
  const float* b_attn = (const float*)d_in[4];
  const float* w_proj = (const float*)d_in[5];
  const float* b_proj = (const float*)d_in[6];
  const float* ln2_w  = (const float*)d_in[7];
  const float* ln2_b  = (const float*)d_in[8];
  const float* w_fc   = (const float*)d_in[9];
  const float* b_fc   = (const float*)d_in[10];
  const float* w_fcp  = (const float*)d_in[11];
  const float* b_fcp  = (const float*)d_in[12];
  float* out = (float*)d_out;

  char* ws = (char*)d_ws;
  // workspace layout (bytes)
  u16*   wt_attn = (u16*)(ws + 0);                      //  [2304][768]  3,538,944
  u16*   wt_proj = (u16*)(ws + 3538944);                //  [768][768]   1,179,648
  u16*   wt_fc   = (u16*)(ws + 4718592);                //  [3072][768]  4,718,592
  u16*   wt_fcp  = (u16*)(ws + 9437184);                //  [768][3072]  4,718,592
  u16*   h_ln    = (u16*)(ws + 14155776);               //  [8192][768] 12,582,912
  u16*   qkv     = (u16*)(ws + 26738688);               //  [8192][2304] 37,748,736
  u16*   vtb     = (u16*)(ws + 64487424);               //  [48][64][2048] 12,582,912
  u16*   h_gelu  = qkv;                                 //  [8192][3072] aliases qkv+vt
  u16*   attn    = (u16*)(ws + 77070336);               //  [8192][768] 12,582,912
  float* x2      = (float*)(ws + 89653248);             //  [8192][768] 25,165,824
  // total 114,819,072 bytes

  // 1) weight transpose + bf16 cast
  k_transpose_w<<<dim3(36, 12), 256, 0, stream>>>(w_attn, wt_attn, 768, 2304);
  k_transpose_w<<<dim3(12, 12), 256, 0, stream>>>(w_proj, wt_proj, 768, 768);
  k_transpose_w<<<dim3(48, 12), 256, 0, stream>>>(w_fc, wt_fc, 768, 3072);
  k_transpose_w<<<dim3(12, 48), 256, 0, stream>>>(w_fcp, wt_fcp, 3072, 768);
  // 2) LN1
  k_layernorm<<<8192, 192, 0, stream>>>(x, ln1_w, ln1_b, h_ln);
  // 3) QKV GEMM
  k_gemm<EPI_QKV><<<dim3(18, 64), 256, 0, stream>>>(h_ln, wt_attn, b_attn, nullptr, qkv, 8192, 2304, 768);
  // 4) V transpose
  k_transpose_v<<<dim3(32, 48), 256, 0, stream>>>(qkv, vtb);
  // 5) attention
  k_attn<<<dim3(32, 12, 4), 256, 0, stream>>>(qkv, vtb, attn);
  // 6) out-proj GEMM + residual -> x2 (fp32)
  k_gemm<EPI_RESID><<<dim3(6, 64), 256, 0, stream>>>(attn, wt_proj, b_proj, x, x2, 8192, 768, 768);
  // 7) LN2
  k_layernorm<<<8192, 192, 0, stream>>>(x2, ln2_w, ln2_b, h_ln);
  // 8) FC GEMM + GELU
  k_gemm<EPI_GELU><<<dim3(24, 64), 256, 0, stream>>>(h_ln, wt_fc, b_fc, nullptr, h_gelu, 8192, 3072, 768);
  // 9) FC-proj GEMM + residual -> out (fp32)
  k_gemm<EPI_RESID><<<dim3(6, 64), 256, 0, stream>>>(h_gelu, wt_fcp, b_fcp, x2, out, 8192, 768, 3072);
}

// Round 3
// 486.501 us; speedup vs baseline: 1.2067x; 1.2067x over previous
//
#include <hip/hip_runtime.h>

typedef __bf16 bf16x8 __attribute__((ext_vector_type(8)));
typedef float f32x4 __attribute__((ext_vector_type(4)));
typedef unsigned short u16;
typedef u16 u16x8 __attribute__((ext_vector_type(8)));
typedef u16 u16x4 __attribute__((ext_vector_type(4)));

#define DEVI static __device__ __forceinline__

// fp32 -> bf16 round-to-nearest-even (bit pattern)
DEVI u16 f2bf(float f) {
  unsigned u = __float_as_uint(f);
  u += 0x7FFFu + ((u >> 16) & 1u);
  return (u16)(u >> 16);
}
DEVI float bf2f(u16 u) { return __uint_as_float(((unsigned)u) << 16); }

DEVI void gload_lds16(const void* g, void* l) {
  __builtin_amdgcn_global_load_lds((const __attribute__((address_space(1))) void*)g,
                                   (__attribute__((address_space(3))) void*)l, 16, 0, 0);
}

// ---------------------------------------------------------------------------
// Transpose fp32 [R][C] -> bf16 [C][R].  Tile 64x64, grid (C/64, R/64).
// ---------------------------------------------------------------------------
__global__ __launch_bounds__(256) void k_transpose_w(const float* __restrict__ in,
                                                     u16* __restrict__ out, int R, int C) {
  __shared__ float tile[64][65];
  const int t = threadIdx.x;
  const int c0 = blockIdx.x * 64, r0 = blockIdx.y * 64;
#pragma unroll
  for (int i = 0; i < 4; ++i) {
    int id = t + i * 256;            // 0..1023 : 64 rows x 16 float4
    int r = id >> 4, c4 = (id & 15) * 4;
    f32x4 v = *(const f32x4*)(in + (size_t)(r0 + r) * C + c0 + c4);
#pragma unroll
    for (int j = 0; j < 4; ++j) tile[r][c4 + j] = v[j];
  }
  __syncthreads();
  const int oc = t >> 2;             // 0..63 : output row (= input col)
  const int rr = (t & 3) * 16;
  u16x8 lo, hi;
#pragma unroll
  for (int j = 0; j < 8; ++j) lo[j] = f2bf(tile[rr + j][oc]);
#pragma unroll
  for (int j = 0; j < 8; ++j) hi[j] = f2bf(tile[rr + 8 + j][oc]);
  u16* dst = out + (size_t)(c0 + oc) * R + r0 + rr;
  *(u16x8*)dst = lo;
  *(u16x8*)(dst + 8) = hi;
}

// ---------------------------------------------------------------------------
// Transpose V slice of qkv (bf16) into vT[B*H][64][2048].  grid (S/64, B*H)
// ---------------------------------------------------------------------------
__global__ __launch_bounds__(256) void k_transpose_v(const u16* __restrict__ qkv,
                                                     u16* __restrict__ vt) {
  __shared__ u16 tile[64][72];
  const int t = threadIdx.x;
  const int bh = blockIdx.y;                 // b*12+h
  const int b = bh / 12, h = bh % 12;
  const int s0 = blockIdx.x * 64;
  const u16* src = qkv + (size_t)b * 2048 * 2304 + 1536 + h * 64;
#pragma unroll
  for (int i = 0; i < 2; ++i) {
    int id = t + i * 256;                    // 0..511 : 64 rows x 8 chunks
    int r = id >> 3, c8 = (id & 7) * 8;
    *(u16x8*)&tile[r][c8] = *(const u16x8*)(src + (size_t)(s0 + r) * 2304 + c8);
  }
  __syncthreads();
  const int od = t >> 2;                     // 0..63 (d)
  const int rr = (t & 3) * 16;
  u16x8 lo, hi;
#pragma unroll
  for (int j = 0; j < 8; ++j) lo[j] = tile[rr + j][od];
#pragma unroll
  for (int j = 0; j < 8; ++j) hi[j] = tile[rr + 8 + j][od];
  u16* dst = vt + ((size_t)bh * 64 + od) * 2048 + s0 + rr;
  *(u16x8*)dst = lo;
  *(u16x8*)(dst + 8) = hi;
}

// ---------------------------------------------------------------------------
// LayerNorm: fp32 [8192][768] -> bf16 [8192][768]. block 192 (1 float4/thread)
// ---------------------------------------------------------------------------
__global__ __launch_bounds__(192) void k_layernorm(const float* __restrict__ x,
                                                   const float* __restrict__ w,
                                                   const float* __restrict__ bvec,
                                                   u16* __restrict__ out) {
  const int row = blockIdx.x, t = threadIdx.x;
  const float* xr = x + (size_t)row * 768;
  f32x4 v = *(const f32x4*)(xr + t * 4);
  float s = v[0] + v[1] + v[2] + v[3];
  float sq = v[0] * v[0] + v[1] * v[1] + v[2] * v[2] + v[3] * v[3];
#pragma unroll
  for (int m = 1; m < 64; m <<= 1) { s += __shfl_xor(s, m); sq += __shfl_xor(sq, m); }
  __shared__ float red[2][3];
  const int wv = t >> 6;
  if ((t & 63) == 0) { red[0][wv] = s; red[1][wv] = sq; }
  __syncthreads();
  s = red[0][0] + red[0][1] + red[0][2];
  sq = red[1][0] + red[1][1] + red[1][2];
  const float mean = s * (1.0f / 768.0f);
  const float var = sq * (1.0f / 768.0f) - mean * mean;
  const float rstd = rsqrtf(var + 1e-5f);
  f32x4 wv4 = *(const f32x4*)(w + t * 4);
  f32x4 bv4 = *(const f32x4*)(bvec + t * 4);
  u16x4 o;
#pragma unroll
  for (int j = 0; j < 4; ++j) o[j] = f2bf((v[j] - mean) * rstd * wv4[j] + bv4[j]);
  *(u16x4*)(out + (size_t)row * 768 + t * 4) = o;
}

// ---------------------------------------------------------------------------
// GEMM: C[M][N] = A[M][K](bf16) * BT[N][K](bf16)^T + bias (+epilogue)
// 128x128 tile, BK=32, 4 waves, m97 structure w/ global_load_lds(16B).
// ---------------------------------------------------------------------------
#define EPI_QKV 0    // bf16 out = val
#define EPI_RESID 1  // f32  out = val + resid
#define EPI_GELU 2   // bf16 out = gelu(val)

template <int EPI>
__global__ __launch_bounds__(256) void k_gemm(const u16* __restrict__ A,
                                              const u16* __restrict__ BT,
                                              const float* __restrict__ bias,
                                              const float* __restrict__ resid,
                                              void* __restrict__ outp,
                                              int M, int N, int K) {
  __shared__ u16 As[128 * 32];
  __shared__ u16 Bs[128 * 32];
  const int t = threadIdx.x;
  const int lane = t & 63, w = t >> 6;
  const int l15 = lane & 15, l4 = lane >> 4;
  const int wr = w >> 1, wc = w & 1;
  const int m0 = blockIdx.y * 128, n0 = blockIdx.x * 128;

  f32x4 acc[4][4] = {};

  for (int kt = 0; kt < K; kt += 32) {
#pragma unroll
    for (int i = 0; i < 2; ++i) {
      int c = w * 128 + i * 64 + lane;       // 16B chunk id, 0..511
      int m = c >> 2, k16 = (c & 3) * 8;
      gload_lds16(A + (size_t)(m0 + m) * K + kt + k16, As + c * 8);
    }
#pragma unroll
    for (int i = 0; i < 2; ++i) {
      int c = w * 128 + i * 64 + lane;
      int n = c >> 2, k16 = (c & 3) * 8;
      gload_lds16(BT + (size_t)(n0 + n) * K + kt + k16, Bs + c * 8);
    }
    __syncthreads();
    bf16x8 af[4], bfr[4];
#pragma unroll
    for (int f = 0; f < 4; ++f)
      af[f] = *(const bf16x8*)(As + (wr * 64 + f * 16 + l15) * 32 + l4 * 8);
#pragma unroll
    for (int f = 0; f < 4; ++f)
      bfr[f] = *(const bf16x8*)(Bs + (wc * 64 + f * 16 + l15) * 32 + l4 * 8);
#pragma unroll
    for (int fi = 0; fi < 4; ++fi)
#pragma unroll
      for (int fj = 0; fj < 4; ++fj)
        acc[fi][fj] = __builtin_amdgcn_mfma_f32_16x16x32_bf16(af[fi], bfr[fj], acc[fi][fj], 0, 0, 0);
    __syncthreads();
  }

#pragma unroll
  for (int fi = 0; fi < 4; ++fi) {
    const int mbase = m0 + wr * 64 + fi * 16 + l4 * 4;
#pragma unroll
    for (int fj = 0; fj < 4; ++fj) {
      const int n = n0 + wc * 64 + fj * 16 + l15;
      const float bn = bias[n];
#pragma unroll
      for (int r = 0; r < 4; ++r) {
        const size_t idx = (size_t)(mbase + r) * N + n;
        float val = acc[fi][fj][r] + bn;
        if constexpr (EPI == EPI_QKV) {
          ((u16*)outp)[idx] = f2bf(val);
        } else if constexpr (EPI == EPI_RESID) {
          ((float*)outp)[idx] = val + resid[idx];
        } else {
          float g = 0.5f * val * (1.0f + tanhf(0.7978845608028654f * (val + 0.044715f * val * val * val)));
          ((u16*)outp)[idx] = f2bf(g);
        }
      }
    }
  }
}

// ---------------------------------------------------------------------------
// Causal flash attention, SWAPPED-QK^T form.  grid (S/64, H, B), 256 thr.
// mfma(K,Q) -> S^T: lane holds (q = lane&15, k = 16c + 4*(lane>>4) + r).
// Row-softmax: 15 fmax + 2 shfl_xor. exp2-domain (Q prescaled by 0.125*log2e).
// P stored row-major [16][72] per wave: 4x ds_write_b64, read 2x ds_read_b128.
// Defer-max: skip o rescale unless pm > m_run + 8.
// ---------------------------------------------------------------------------
__global__ __launch_bounds__(256) void k_attn(const u16* __restrict__ qkv,
                                              const u16* __restrict__ vt,
                                              u16* __restrict__ out) {
  __shared__ u16 Ks[64 * 72];
  __shared__ u16 Vs[64 * 72];
  __shared__ u16 Ps[4][16 * 72];
  const int t = threadIdx.x, lane = t & 63, w = t >> 6;
  const int l15 = lane & 15, l4 = lane >> 4;
  const int l44 = l4 * 4;
  const int qt = blockIdx.x, h = blockIdx.y, b = blockIdx.z;
  const int q0 = qt * 64;
  const u16* qbase = qkv + (size_t)b * 2048 * 2304 + h * 64;
  const u16* kbase = qbase + 768;
  const u16* vtb = vt + ((size_t)(b * 12 + h) * 64) * 2048;

  // Q fragment (B-operand rows = q), prescaled by 1/sqrt(64) * log2(e)
  const int qrow = q0 + w * 16 + l15;
  bf16x8 qf0, qf1;
  {
    const float PRE = 0.18033688011112042f;  // 0.125 * log2(e)
    u16x8 r0 = *(const u16x8*)(qbase + (size_t)qrow * 2304 + l4 * 8);
    u16x8 r1 = *(const u16x8*)(qbase + (size_t)qrow * 2304 + 32 + l4 * 8);
    u16x8 s0, s1;
#pragma unroll
    for (int j = 0; j < 8; ++j) { s0[j] = f2bf(bf2f(r0[j]) * PRE); s1[j] = f2bf(bf2f(r1[j]) * PRE); }
    qf0 = *(bf16x8*)&s0;
    qf1 = *(bf16x8*)&s1;
  }

  float m_run = -1e30f, l_run = 0.f;
  f32x4 o_acc[4] = {};
  u16* pw = &Ps[w][0];
  const int qq = w * 16 + l15;   // q_local for causal mask

  for (int kt = 0; kt <= qt; ++kt) {
    const int kv0 = kt * 64;
#pragma unroll
    for (int i = 0; i < 2; ++i) {
      int id = t + i * 256;
      int r = id >> 3, c8 = (id & 7) * 8;
      *(u16x8*)&Ks[r * 72 + c8] = *(const u16x8*)(kbase + (size_t)(kv0 + r) * 2304 + c8);
      *(u16x8*)&Vs[r * 72 + c8] = *(const u16x8*)(vtb + (size_t)r * 2048 + kv0 + c8);
    }
    __syncthreads();

    // S^T = K * Q^T  (A = K rows->k, B = Q rows->q)
    f32x4 sa[4] = {};
#pragma unroll
    for (int c = 0; c < 4; ++c) {
      bf16x8 kf0 = *(const bf16x8*)(Ks + (c * 16 + l15) * 72 + l4 * 8);
      bf16x8 kf1 = *(const bf16x8*)(Ks + (c * 16 + l15) * 72 + 32 + l4 * 8);
      sa[c] = __builtin_amdgcn_mfma_f32_16x16x32_bf16(kf0, qf0, sa[c], 0, 0, 0);
      sa[c] = __builtin_amdgcn_mfma_f32_16x16x32_bf16(kf1, qf1, sa[c], 0, 0, 0);
    }

    if (kt == qt) {  // wave-uniform: only the diagonal tile masks
#pragma unroll
      for (int c = 0; c < 4; ++c)
#pragma unroll
        for (int r = 0; r < 4; ++r)
          if (c * 16 + l44 + r > qq) sa[c][r] = -1e30f;
    }

    // row max (row = q = l15): in-lane over 16, then cross-l4
    float pm = fmaxf(fmaxf(sa[0][0], sa[0][1]), fmaxf(sa[0][2], sa[0][3]));
#pragma unroll
    for (int c = 1; c < 4; ++c)
      pm = fmaxf(pm, fmaxf(fmaxf(sa[c][0], sa[c][1]), fmaxf(sa[c][2], sa[c][3])));
    pm = fmaxf(pm, __shfl_xor(pm, 16));
    pm = fmaxf(pm, __shfl_xor(pm, 32));

    // defer-max rescale (log2-domain threshold 8 -> P bounded by 256)
    if (__any(pm > m_run + 8.0f)) {
      float mn = fmaxf(m_run, pm);
      float scq = exp2f(m_run - mn);
      m_run = mn;
      l_run *= scq;
#pragma unroll
      for (int r = 0; r < 4; ++r) {
        float s = __shfl(scq, l44 + r);   // o rows are q = 4*l4 + r
#pragma unroll
        for (int cd = 0; cd < 4; ++cd) o_acc[cd][r] *= s;
      }
    }

    // P = exp2(S - m), row-sum, pack to bf16
    float ls = 0.f;
    u16x4 pk[4];
#pragma unroll
    for (int c = 0; c < 4; ++c)
#pragma unroll
      for (int r = 0; r < 4; ++r) {
        float p = exp2f(sa[c][r] - m_run);
        ls += p;
        pk[c][r] = f2bf(p);
      }
    ls += __shfl_xor(ls, 16);
    ls += __shfl_xor(ls, 32);
    l_run += ls;

    // store P row-major [q=16][72]: lane writes 4 consecutive k per c (b64)
#pragma unroll
    for (int c = 0; c < 4; ++c)
      *(u16x4*)(pw + l15 * 72 + c * 16 + l44) = pk[c];

    bf16x8 pa0 = *(const bf16x8*)(pw + l15 * 72 + l4 * 8);
    bf16x8 pa1 = *(const bf16x8*)(pw + l15 * 72 + 32 + l4 * 8);

#pragma unroll
    for (int cd = 0; cd < 4; ++cd) {
      bf16x8 vf0 = *(const bf16x8*)(Vs + (cd * 16 + l15) * 72 + l4 * 8);
      bf16x8 vf1 = *(const bf16x8*)(Vs + (cd * 16 + l15) * 72 + 32 + l4 * 8);
      o_acc[cd] = __builtin_amdgcn_mfma_f32_16x16x32_bf16(pa0, vf0, o_acc[cd], 0, 0, 0);
      o_acc[cd] = __builtin_amdgcn_mfma_f32_16x16x32_bf16(pa1, vf1, o_acc[cd], 0, 0, 0);
    }
    __syncthreads();
  }

  // epilogue: O rows q = q0 + w*16 + 4*l4 + r; cols d = cd*16 + l15
  float lr[4];
#pragma unroll
  for (int r = 0; r < 4; ++r) lr[r] = 1.0f / __shfl(l_run, l44 + r);
#pragma unroll
  for (int cd = 0; cd < 4; ++cd)
#pragma unroll
    for (int r = 0; r < 4; ++r) {
      int qr = q0 + w * 16 + l44 + r;
      out[((size_t)(b * 2048) + qr) * 768 + h * 64 + cd * 16 + l15] = f2bf(o_acc[cd][r] * lr[r]);
    }
}

// ---------------------------------------------------------------------------
extern "C" void kernel_launch(void* const* d_in, const int* in_sizes, int n_in,
                              void* d_out, int out_size, void* d_ws, size_t ws_size,
                              hipStream_t stream) {
  (void)in_sizes; (void)n_in; (void)out_size; (void)ws_size;
  const float* x      = (const float*)d_in[0];
  const float* ln1_w  = (const float*)d_in[1];
  const float* ln1_b  = (const float*)d_in[2];
  const float* w_attn = (const float*)d_in[3];
  const float* b_attn = (const float*)d_in[4];
  const float* w_proj = (const float*)d_in[5];
  const float* b_proj = (const float*)d_in[6];
  const float* ln2_w  = (const float*)d_in[7];
  const float* ln2_b  = (const float*)d_in[8];
  const float* w_fc   = (const float*)d_in[9];
  const float* b_fc   = (const float*)d_in[10];
  const float* w_fcp  = (const float*)d_in[11];
  const float* b_fcp  = (const float*)d_in[12];
  float* out = (float*)d_out;

  char* ws = (char*)d_ws;
  // workspace layout (bytes)
  u16*   wt_attn = (u16*)(ws + 0);                      //  [2304][768]  3,538,944
  u16*   wt_proj = (u16*)(ws + 3538944);                //  [768][768]   1,179,648
  u16*   wt_fc   = (u16*)(ws + 4718592);                //  [3072][768]  4,718,592
  u16*   wt_fcp  = (u16*)(ws + 9437184);                //  [768][3072]  4,718,592
  u16*   h_ln    = (u16*)(ws + 14155776);               //  [8192][768] 12,582,912
  u16*   qkv     = (u16*)(ws + 26738688);               //  [8192][2304] 37,748,736
  u16*   vtb     = (u16*)(ws + 64487424);               //  [48][64][2048] 12,582,912
  u16*   h_gelu  = qkv;                                 //  [8192][3072] aliases qkv+vt
  u16*   attn    = (u16*)(ws + 77070336);               //  [8192][768] 12,582,912
  float* x2      = (float*)(ws + 89653248);             //  [8192][768] 25,165,824
  // total 114,819,072 bytes

  // 1) weight transpose + bf16 cast
  k_transpose_w<<<dim3(36, 12), 256, 0, stream>>>(w_attn, wt_attn, 768, 2304);
  k_transpose_w<<<dim3(12, 12), 256, 0, stream>>>(w_proj, wt_proj, 768, 768);
  k_transpose_w<<<dim3(48, 12), 256, 0, stream>>>(w_fc, wt_fc, 768, 3072);
  k_transpose_w<<<dim3(12, 48), 256, 0, stream>>>(w_fcp, wt_fcp, 3072, 768);
  // 2) LN1
  k_layernorm<<<8192, 192, 0, stream>>>(x, ln1_w, ln1_b, h_ln);
  // 3) QKV GEMM
  k_gemm<EPI_QKV><<<dim3(18, 64), 256, 0, stream>>>(h_ln, wt_attn, b_attn, nullptr, qkv, 8192, 2304, 768);
  // 4) V transpose
  k_transpose_v<<<dim3(32, 48), 256, 0, stream>>>(qkv, vtb);
  // 5) attention
  k_attn<<<dim3(32, 12, 4), 256, 0, stream>>>(qkv, vtb, attn);
  // 6) out-proj GEMM + residual -> x2 (fp32)
  k_gemm<EPI_RESID><<<dim3(6, 64), 256, 0, stream>>>(attn, wt_proj, b_proj, x, x2, 8192, 768, 768);
  // 7) LN2
  k_layernorm<<<8192, 192, 0, stream>>>(x2, ln2_w, ln2_b, h_ln);
  // 8) FC GEMM + GELU
  k_gemm<EPI_GELU><<<dim3(24, 64), 256, 0, stream>>>(h_ln, wt_fc, b_fc, nullptr, h_gelu, 8192, 3072, 768);
  // 9) FC-proj GEMM + residual -> out (fp32)
  k_gemm<EPI_RESID><<<dim3(6, 64), 256, 0, stream>>>(h_gelu, wt_fcp, b_fcp, x2, out, 8192, 768, 3072);
}

// Round 4
// 475.089 us; speedup vs baseline: 1.2357x; 1.0240x over previous
//
#include <hip/hip_runtime.h>

typedef __bf16 bf16x8 __attribute__((ext_vector_type(8)));
typedef float f32x4 __attribute__((ext_vector_type(4)));
typedef unsigned short u16;
typedef u16 u16x8 __attribute__((ext_vector_type(8)));
typedef u16 u16x4 __attribute__((ext_vector_type(4)));

#define DEVI static __device__ __forceinline__

// fp32 -> bf16 round-to-nearest-even (bit pattern)
DEVI u16 f2bf(float f) {
  unsigned u = __float_as_uint(f);
  u += 0x7FFFu + ((u >> 16) & 1u);
  return (u16)(u >> 16);
}
DEVI float bf2f(u16 u) { return __uint_as_float(((unsigned)u) << 16); }

DEVI void gload_lds16(const void* g, void* l) {
  __builtin_amdgcn_global_load_lds((const __attribute__((address_space(1))) void*)g,
                                   (__attribute__((address_space(3))) void*)l, 16, 0, 0);
}

// ---------------------------------------------------------------------------
// Transpose fp32 [R][C] -> bf16 [C][R].  Tile 64x64, grid (C/64, R/64).
// ---------------------------------------------------------------------------
__global__ __launch_bounds__(256) void k_transpose_w(const float* __restrict__ in,
                                                     u16* __restrict__ out, int R, int C) {
  __shared__ float tile[64][65];
  const int t = threadIdx.x;
  const int c0 = blockIdx.x * 64, r0 = blockIdx.y * 64;
#pragma unroll
  for (int i = 0; i < 4; ++i) {
    int id = t + i * 256;            // 0..1023 : 64 rows x 16 float4
    int r = id >> 4, c4 = (id & 15) * 4;
    f32x4 v = *(const f32x4*)(in + (size_t)(r0 + r) * C + c0 + c4);
#pragma unroll
    for (int j = 0; j < 4; ++j) tile[r][c4 + j] = v[j];
  }
  __syncthreads();
  const int oc = t >> 2;             // 0..63 : output row (= input col)
  const int rr = (t & 3) * 16;
  u16x8 lo, hi;
#pragma unroll
  for (int j = 0; j < 8; ++j) lo[j] = f2bf(tile[rr + j][oc]);
#pragma unroll
  for (int j = 0; j < 8; ++j) hi[j] = f2bf(tile[rr + 8 + j][oc]);
  u16* dst = out + (size_t)(c0 + oc) * R + r0 + rr;
  *(u16x8*)dst = lo;
  *(u16x8*)(dst + 8) = hi;
}

// ---------------------------------------------------------------------------
// Transpose V slice of qkv (bf16) into vT[B*H][64][2048].  grid (S/64, B*H)
// ---------------------------------------------------------------------------
__global__ __launch_bounds__(256) void k_transpose_v(const u16* __restrict__ qkv,
                                                     u16* __restrict__ vt) {
  __shared__ u16 tile[64][72];
  const int t = threadIdx.x;
  const int bh = blockIdx.y;                 // b*12+h
  const int b = bh / 12, h = bh % 12;
  const int s0 = blockIdx.x * 64;
  const u16* src = qkv + (size_t)b * 2048 * 2304 + 1536 + h * 64;
#pragma unroll
  for (int i = 0; i < 2; ++i) {
    int id = t + i * 256;                    // 0..511 : 64 rows x 8 chunks
    int r = id >> 3, c8 = (id & 7) * 8;
    *(u16x8*)&tile[r][c8] = *(const u16x8*)(src + (size_t)(s0 + r) * 2304 + c8);
  }
  __syncthreads();
  const int od = t >> 2;                     // 0..63 (d)
  const int rr = (t & 3) * 16;
  u16x8 lo, hi;
#pragma unroll
  for (int j = 0; j < 8; ++j) lo[j] = tile[rr + j][od];
#pragma unroll
  for (int j = 0; j < 8; ++j) hi[j] = tile[rr + 8 + j][od];
  u16* dst = vt + ((size_t)bh * 64 + od) * 2048 + s0 + rr;
  *(u16x8*)dst = lo;
  *(u16x8*)(dst + 8) = hi;
}

// ---------------------------------------------------------------------------
// LayerNorm: fp32 [8192][768] -> bf16 [8192][768]. block 192 (1 float4/thread)
// ---------------------------------------------------------------------------
__global__ __launch_bounds__(192) void k_layernorm(const float* __restrict__ x,
                                                   const float* __restrict__ w,
                                                   const float* __restrict__ bvec,
                                                   u16* __restrict__ out) {
  const int row = blockIdx.x, t = threadIdx.x;
  const float* xr = x + (size_t)row * 768;
  f32x4 v = *(const f32x4*)(xr + t * 4);
  float s = v[0] + v[1] + v[2] + v[3];
  float sq = v[0] * v[0] + v[1] * v[1] + v[2] * v[2] + v[3] * v[3];
#pragma unroll
  for (int m = 1; m < 64; m <<= 1) { s += __shfl_xor(s, m); sq += __shfl_xor(sq, m); }
  __shared__ float red[2][3];
  const int wv = t >> 6;
  if ((t & 63) == 0) { red[0][wv] = s; red[1][wv] = sq; }
  __syncthreads();
  s = red[0][0] + red[0][1] + red[0][2];
  sq = red[1][0] + red[1][1] + red[1][2];
  const float mean = s * (1.0f / 768.0f);
  const float var = sq * (1.0f / 768.0f) - mean * mean;
  const float rstd = rsqrtf(var + 1e-5f);
  f32x4 wv4 = *(const f32x4*)(w + t * 4);
  f32x4 bv4 = *(const f32x4*)(bvec + t * 4);
  u16x4 o;
#pragma unroll
  for (int j = 0; j < 4; ++j) o[j] = f2bf((v[j] - mean) * rstd * wv4[j] + bv4[j]);
  *(u16x4*)(out + (size_t)row * 768 + t * 4) = o;
}

// ---------------------------------------------------------------------------
// GEMM: C[M][N] = A[M][K](bf16) * BT[N][K](bf16)^T + bias (+epilogue)
// 128x128 tile, BK=32, 4 waves, m97 structure w/ global_load_lds(16B).
// ---------------------------------------------------------------------------
#define EPI_QKV 0    // bf16 out = val
#define EPI_RESID 1  // f32  out = val + resid
#define EPI_GELU 2   // bf16 out = gelu(val)

template <int EPI>
__global__ __launch_bounds__(256) void k_gemm(const u16* __restrict__ A,
                                              const u16* __restrict__ BT,
                                              const float* __restrict__ bias,
                                              const float* __restrict__ resid,
                                              void* __restrict__ outp,
                                              int M, int N, int K) {
  __shared__ u16 As[128 * 32];
  __shared__ u16 Bs[128 * 32];
  const int t = threadIdx.x;
  const int lane = t & 63, w = t >> 6;
  const int l15 = lane & 15, l4 = lane >> 4;
  const int wr = w >> 1, wc = w & 1;
  const int m0 = blockIdx.y * 128, n0 = blockIdx.x * 128;

  f32x4 acc[4][4] = {};

  for (int kt = 0; kt < K; kt += 32) {
#pragma unroll
    for (int i = 0; i < 2; ++i) {
      int c = w * 128 + i * 64 + lane;       // 16B chunk id, 0..511
      int m = c >> 2, k16 = (c & 3) * 8;
      gload_lds16(A + (size_t)(m0 + m) * K + kt + k16, As + c * 8);
    }
#pragma unroll
    for (int i = 0; i < 2; ++i) {
      int c = w * 128 + i * 64 + lane;
      int n = c >> 2, k16 = (c & 3) * 8;
      gload_lds16(BT + (size_t)(n0 + n) * K + kt + k16, Bs + c * 8);
    }
    __syncthreads();
    bf16x8 af[4], bfr[4];
#pragma unroll
    for (int f = 0; f < 4; ++f)
      af[f] = *(const bf16x8*)(As + (wr * 64 + f * 16 + l15) * 32 + l4 * 8);
#pragma unroll
    for (int f = 0; f < 4; ++f)
      bfr[f] = *(const bf16x8*)(Bs + (wc * 64 + f * 16 + l15) * 32 + l4 * 8);
#pragma unroll
    for (int fi = 0; fi < 4; ++fi)
#pragma unroll
      for (int fj = 0; fj < 4; ++fj)
        acc[fi][fj] = __builtin_amdgcn_mfma_f32_16x16x32_bf16(af[fi], bfr[fj], acc[fi][fj], 0, 0, 0);
    __syncthreads();
  }

#pragma unroll
  for (int fi = 0; fi < 4; ++fi) {
    const int mbase = m0 + wr * 64 + fi * 16 + l4 * 4;
#pragma unroll
    for (int fj = 0; fj < 4; ++fj) {
      const int n = n0 + wc * 64 + fj * 16 + l15;
      const float bn = bias[n];
#pragma unroll
      for (int r = 0; r < 4; ++r) {
        const size_t idx = (size_t)(mbase + r) * N + n;
        float val = acc[fi][fj][r] + bn;
        if constexpr (EPI == EPI_QKV) {
          ((u16*)outp)[idx] = f2bf(val);
        } else if constexpr (EPI == EPI_RESID) {
          ((float*)outp)[idx] = val + resid[idx];
        } else {
          float g = 0.5f * val * (1.0f + tanhf(0.7978845608028654f * (val + 0.044715f * val * val * val)));
          ((u16*)outp)[idx] = f2bf(g);
        }
      }
    }
  }
}

// ---------------------------------------------------------------------------
// Causal flash attention, SWAPPED-QK^T, QBLK=128 (8 waves share K/V tile).
// grid (S/128, H, B), 512 thr.  Wave w owns q rows q0+16w .. q0+16w+15.
// mfma(K,Q) -> S^T: lane holds (q = lane&15, k = 16c + 4*(lane>>4) + r).
// Early-out: waves with kv0 > qw+15 stage+barrier only.
// ---------------------------------------------------------------------------
__global__ __launch_bounds__(512) void k_attn(const u16* __restrict__ qkv,
                                              const u16* __restrict__ vt,
                                              u16* __restrict__ out) {
  __shared__ u16 Ks[64 * 72];
  __shared__ u16 Vs[64 * 72];
  __shared__ u16 Ps[8][16 * 72];
  const int t = threadIdx.x, lane = t & 63, w = t >> 6;   // w 0..7
  const int l15 = lane & 15, l4 = lane >> 4;
  const int l44 = l4 * 4;
  const int qb = blockIdx.x, h = blockIdx.y, b = blockIdx.z;
  const int q0 = qb * 128;
  const int qw = q0 + w * 16;              // wave's first q row
  const u16* qbase = qkv + (size_t)b * 2048 * 2304 + h * 64;
  const u16* kbase = qbase + 768;
  const u16* vtb = vt + ((size_t)(b * 12 + h) * 64) * 2048;

  // Q fragment (B-operand rows = q), prescaled by 1/sqrt(64) * log2(e)
  const int qrow = qw + l15;
  bf16x8 qf0, qf1;
  {
    const float PRE = 0.18033688011112042f;  // 0.125 * log2(e)
    u16x8 r0 = *(const u16x8*)(qbase + (size_t)qrow * 2304 + l4 * 8);
    u16x8 r1 = *(const u16x8*)(qbase + (size_t)qrow * 2304 + 32 + l4 * 8);
    u16x8 s0, s1;
#pragma unroll
    for (int j = 0; j < 8; ++j) { s0[j] = f2bf(bf2f(r0[j]) * PRE); s1[j] = f2bf(bf2f(r1[j]) * PRE); }
    qf0 = *(bf16x8*)&s0;
    qf1 = *(bf16x8*)&s1;
  }

  float m_run = -1e30f, l_run = 0.f;
  f32x4 o_acc[4] = {};
  u16* pw = &Ps[w][0];
  const int qq = qw + l15;                 // global q row (causal mask)

  const int ntiles = 2 * qb + 2;           // kv0 = 0 .. (2qb+1)*64
  // staging: 512 threads, 1 chunk (16B) of K and V each
  const int sr = t >> 3, sc8 = (t & 7) * 8;

  for (int kt = 0; kt < ntiles; ++kt) {
    const int kv0 = kt * 64;
    *(u16x8*)&Ks[sr * 72 + sc8] = *(const u16x8*)(kbase + (size_t)(kv0 + sr) * 2304 + sc8);
    *(u16x8*)&Vs[sr * 72 + sc8] = *(const u16x8*)(vtb + (size_t)sr * 2048 + kv0 + sc8);
    __syncthreads();

    if (kv0 <= qw + 15) {                  // wave has live rows in this tile
      // S^T = K * Q^T  (A = K rows->k, B = Q rows->q)
      f32x4 sa[4] = {};
#pragma unroll
      for (int c = 0; c < 4; ++c) {
        bf16x8 kf0 = *(const bf16x8*)(Ks + (c * 16 + l15) * 72 + l4 * 8);
        bf16x8 kf1 = *(const bf16x8*)(Ks + (c * 16 + l15) * 72 + 32 + l4 * 8);
        sa[c] = __builtin_amdgcn_mfma_f32_16x16x32_bf16(kf0, qf0, sa[c], 0, 0, 0);
        sa[c] = __builtin_amdgcn_mfma_f32_16x16x32_bf16(kf1, qf1, sa[c], 0, 0, 0);
      }

      if (kv0 + 63 > qw) {                 // wave-uniform: partial (diagonal) tile
#pragma unroll
        for (int c = 0; c < 4; ++c)
#pragma unroll
          for (int r = 0; r < 4; ++r)
            if (kv0 + c * 16 + l44 + r > qq) sa[c][r] = -1e30f;
      }

      // row max (row = q = l15): in-lane over 16, then cross-l4
      float pm = fmaxf(fmaxf(sa[0][0], sa[0][1]), fmaxf(sa[0][2], sa[0][3]));
#pragma unroll
      for (int c = 1; c < 4; ++c)
        pm = fmaxf(pm, fmaxf(fmaxf(sa[c][0], sa[c][1]), fmaxf(sa[c][2], sa[c][3])));
      pm = fmaxf(pm, __shfl_xor(pm, 16));
      pm = fmaxf(pm, __shfl_xor(pm, 32));

      // defer-max rescale (log2-domain threshold 8 -> P bounded by 256)
      if (__any(pm > m_run + 8.0f)) {
        float mn = fmaxf(m_run, pm);
        float scq = exp2f(m_run - mn);
        m_run = mn;
        l_run *= scq;
#pragma unroll
        for (int r = 0; r < 4; ++r) {
          float s = __shfl(scq, l44 + r);  // o rows are q = 4*l4 + r
#pragma unroll
          for (int cd = 0; cd < 4; ++cd) o_acc[cd][r] *= s;
        }
      }

      // P = exp2(S - m), row-sum, pack to bf16
      float ls = 0.f;
      u16x4 pk[4];
#pragma unroll
      for (int c = 0; c < 4; ++c)
#pragma unroll
        for (int r = 0; r < 4; ++r) {
          float p = exp2f(sa[c][r] - m_run);
          ls += p;
          pk[c][r] = f2bf(p);
        }
      ls += __shfl_xor(ls, 16);
      ls += __shfl_xor(ls, 32);
      l_run += ls;

      // store P row-major [q=16][72]: lane writes 4 consecutive k per c (b64)
#pragma unroll
      for (int c = 0; c < 4; ++c)
        *(u16x4*)(pw + l15 * 72 + c * 16 + l44) = pk[c];

      bf16x8 pa0 = *(const bf16x8*)(pw + l15 * 72 + l4 * 8);
      bf16x8 pa1 = *(const bf16x8*)(pw + l15 * 72 + 32 + l4 * 8);

#pragma unroll
      for (int cd = 0; cd < 4; ++cd) {
        bf16x8 vf0 = *(const bf16x8*)(Vs + (cd * 16 + l15) * 72 + l4 * 8);
        bf16x8 vf1 = *(const bf16x8*)(Vs + (cd * 16 + l15) * 72 + 32 + l4 * 8);
        o_acc[cd] = __builtin_amdgcn_mfma_f32_16x16x32_bf16(pa0, vf0, o_acc[cd], 0, 0, 0);
        o_acc[cd] = __builtin_amdgcn_mfma_f32_16x16x32_bf16(pa1, vf1, o_acc[cd], 0, 0, 0);
      }
    }
    __syncthreads();
  }

  // epilogue: O rows q = qw + 4*l4 + r; cols d = cd*16 + l15
  float lr[4];
#pragma unroll
  for (int r = 0; r < 4; ++r) lr[r] = 1.0f / __shfl(l_run, l44 + r);
#pragma unroll
  for (int cd = 0; cd < 4; ++cd)
#pragma unroll
    for (int r = 0; r < 4; ++r) {
      int qr = qw + l44 + r;
      out[((size_t)(b * 2048) + qr) * 768 + h * 64 + cd * 16 + l15] = f2bf(o_acc[cd][r] * lr[r]);
    }
}

// ---------------------------------------------------------------------------
extern "C" void kernel_launch(void* const* d_in, const int* in_sizes, int n_in,
                              void* d_out, int out_size, void* d_ws, size_t ws_size,
                              hipStream_t stream) {
  (void)in_sizes; (void)n_in; (void)out_size; (void)ws_size;
  const float* x      = (const float*)d_in[0];
  const float* ln1_w  = (const float*)d_in[1];
  const float* ln1_b  = (const float*)d_in[2];
  const float* w_attn = (const float*)d_in[3];
  const float* b_attn = (const float*)d_in[4];
  const float* w_proj = (const float*)d_in[5];
  const float* b_proj = (const float*)d_in[6];
  const float* ln2_w  = (const float*)d_in[7];
  const float* ln2_b  = (const float*)d_in[8];
  const float* w_fc   = (const float*)d_in[9];
  const float* b_fc   = (const float*)d_in[10];
  const float* w_fcp  = (const float*)d_in[11];
  const float* b_fcp  = (const float*)d_in[12];
  float* out = (float*)d_out;

  char* ws = (char*)d_ws;
  // workspace layout (bytes)
  u16*   wt_attn = (u16*)(ws + 0);                      //  [2304][768]  3,538,944
  u16*   wt_proj = (u16*)(ws + 3538944);                //  [768][768]   1,179,648
  u16*   wt_fc   = (u16*)(ws + 4718592);                //  [3072][768]  4,718,592
  u16*   wt_fcp  = (u16*)(ws + 9437184);                //  [768][3072]  4,718,592
  u16*   h_ln    = (u16*)(ws + 14155776);               //  [8192][768] 12,582,912
  u16*   qkv     = (u16*)(ws + 26738688);               //  [8192][2304] 37,748,736
  u16*   vtb     = (u16*)(ws + 64487424);               //  [48][64][2048] 12,582,912
  u16*   h_gelu  = qkv;                                 //  [8192][3072] aliases qkv+vt
  u16*   attn    = (u16*)(ws + 77070336);               //  [8192][768] 12,582,912
  float* x2      = (float*)(ws + 89653248);             //  [8192][768] 25,165,824
  // total 114,819,072 bytes

  // 1) weight transpose + bf16 cast
  k_transpose_w<<<dim3(36, 12), 256, 0, stream>>>(w_attn, wt_attn, 768, 2304);
  k_transpose_w<<<dim3(12, 12), 256, 0, stream>>>(w_proj, wt_proj, 768, 768);
  k_transpose_w<<<dim3(48, 12), 256, 0, stream>>>(w_fc, wt_fc, 768, 3072);
  k_transpose_w<<<dim3(12, 48), 256, 0, stream>>>(w_fcp, wt_fcp, 3072, 768);
  // 2) LN1
  k_layernorm<<<8192, 192, 0, stream>>>(x, ln1_w, ln1_b, h_ln);
  // 3) QKV GEMM
  k_gemm<EPI_QKV><<<dim3(18, 64), 256, 0, stream>>>(h_ln, wt_attn, b_attn, nullptr, qkv, 8192, 2304, 768);
  // 4) V transpose
  k_transpose_v<<<dim3(32, 48), 256, 0, stream>>>(qkv, vtb);
  // 5) attention (QBLK=128, 8 waves)
  k_attn<<<dim3(16, 12, 4), 512, 0, stream>>>(qkv, vtb, attn);
  // 6) out-proj GEMM + residual -> x2 (fp32)
  k_gemm<EPI_RESID><<<dim3(6, 64), 256, 0, stream>>>(attn, wt_proj, b_proj, x, x2, 8192, 768, 768);
  // 7) LN2
  k_layernorm<<<8192, 192, 0, stream>>>(x2, ln2_w, ln2_b, h_ln);
  // 8) FC GEMM + GELU
  k_gemm<EPI_GELU><<<dim3(24, 64), 256, 0, stream>>>(h_ln, wt_fc, b_fc, nullptr, h_gelu, 8192, 3072, 768);
  // 9) FC-proj GEMM + residual -> out (fp32)
  k_gemm<EPI_RESID><<<dim3(6, 64), 256, 0, stream>>>(h_gelu, wt_fcp, b_fcp, x2, out, 8192, 768, 3072);
}

// Round 7
// 472.451 us; speedup vs baseline: 1.2426x; 1.0056x over previous
//
#include <hip/hip_runtime.h>

typedef __bf16 bf16x8 __attribute__((ext_vector_type(8)));
typedef float f32x4 __attribute__((ext_vector_type(4)));
typedef unsigned short u16;
typedef u16 u16x8 __attribute__((ext_vector_type(8)));
typedef u16 u16x4 __attribute__((ext_vector_type(4)));

#define DEVI static __device__ __forceinline__

// fp32 -> bf16 round-to-nearest-even (bit pattern)
DEVI u16 f2bf(float f) {
  unsigned u = __float_as_uint(f);
  u += 0x7FFFu + ((u >> 16) & 1u);
  return (u16)(u >> 16);
}
DEVI float bf2f(u16 u) { return __uint_as_float(((unsigned)u) << 16); }

DEVI void gload_lds16(const void* g, void* l) {
  __builtin_amdgcn_global_load_lds((const __attribute__((address_space(1))) void*)g,
                                   (__attribute__((address_space(3))) void*)l, 16, 0, 0);
}

// ---------------------------------------------------------------------------
// Transpose fp32 [R][C] -> bf16 [C][R].  Tile 64x64, grid (C/64, R/64).
// ---------------------------------------------------------------------------
__global__ __launch_bounds__(256) void k_transpose_w(const float* __restrict__ in,
                                                     u16* __restrict__ out, int R, int C) {
  __shared__ float tile[64][65];
  const int t = threadIdx.x;
  const int c0 = blockIdx.x * 64, r0 = blockIdx.y * 64;
#pragma unroll
  for (int i = 0; i < 4; ++i) {
    int id = t + i * 256;            // 0..1023 : 64 rows x 16 float4
    int r = id >> 4, c4 = (id & 15) * 4;
    f32x4 v = *(const f32x4*)(in + (size_t)(r0 + r) * C + c0 + c4);
#pragma unroll
    for (int j = 0; j < 4; ++j) tile[r][c4 + j] = v[j];
  }
  __syncthreads();
  const int oc = t >> 2;             // 0..63 : output row (= input col)
  const int rr = (t & 3) * 16;
  u16x8 lo, hi;
#pragma unroll
  for (int j = 0; j < 8; ++j) lo[j] = f2bf(tile[rr + j][oc]);
#pragma unroll
  for (int j = 0; j < 8; ++j) hi[j] = f2bf(tile[rr + 8 + j][oc]);
  u16* dst = out + (size_t)(c0 + oc) * R + r0 + rr;
  *(u16x8*)dst = lo;
  *(u16x8*)(dst + 8) = hi;
}

// ---------------------------------------------------------------------------
// Transpose V slice of qkv (bf16) into vT[B*H][64][2048].  grid (S/64, B*H)
// ---------------------------------------------------------------------------
__global__ __launch_bounds__(256) void k_transpose_v(const u16* __restrict__ qkv,
                                                     u16* __restrict__ vt) {
  __shared__ u16 tile[64][72];
  const int t = threadIdx.x;
  const int bh = blockIdx.y;                 // b*12+h
  const int b = bh / 12, h = bh % 12;
  const int s0 = blockIdx.x * 64;
  const u16* src = qkv + (size_t)b * 2048 * 2304 + 1536 + h * 64;
#pragma unroll
  for (int i = 0; i < 2; ++i) {
    int id = t + i * 256;                    // 0..511 : 64 rows x 8 chunks
    int r = id >> 3, c8 = (id & 7) * 8;
    *(u16x8*)&tile[r][c8] = *(const u16x8*)(src + (size_t)(s0 + r) * 2304 + c8);
  }
  __syncthreads();
  const int od = t >> 2;                     // 0..63 (d)
  const int rr = (t & 3) * 16;
  u16x8 lo, hi;
#pragma unroll
  for (int j = 0; j < 8; ++j) lo[j] = tile[rr + j][od];
#pragma unroll
  for (int j = 0; j < 8; ++j) hi[j] = tile[rr + 8 + j][od];
  u16* dst = vt + ((size_t)bh * 64 + od) * 2048 + s0 + rr;
  *(u16x8*)dst = lo;
  *(u16x8*)(dst + 8) = hi;
}

// ---------------------------------------------------------------------------
// LayerNorm: fp32 [8192][768] -> bf16 [8192][768]. block 192 (1 float4/thread)
// ---------------------------------------------------------------------------
__global__ __launch_bounds__(192) void k_layernorm(const float* __restrict__ x,
                                                   const float* __restrict__ w,
                                                   const float* __restrict__ bvec,
                                                   u16* __restrict__ out) {
  const int row = blockIdx.x, t = threadIdx.x;
  const float* xr = x + (size_t)row * 768;
  f32x4 v = *(const f32x4*)(xr + t * 4);
  float s = v[0] + v[1] + v[2] + v[3];
  float sq = v[0] * v[0] + v[1] * v[1] + v[2] * v[2] + v[3] * v[3];
#pragma unroll
  for (int m = 1; m < 64; m <<= 1) { s += __shfl_xor(s, m); sq += __shfl_xor(sq, m); }
  __shared__ float red[2][3];
  const int wv = t >> 6;
  if ((t & 63) == 0) { red[0][wv] = s; red[1][wv] = sq; }
  __syncthreads();
  s = red[0][0] + red[0][1] + red[0][2];
  sq = red[1][0] + red[1][1] + red[1][2];
  const float mean = s * (1.0f / 768.0f);
  const float var = sq * (1.0f / 768.0f) - mean * mean;
  const float rstd = rsqrtf(var + 1e-5f);
  f32x4 wv4 = *(const f32x4*)(w + t * 4);
  f32x4 bv4 = *(const f32x4*)(bvec + t * 4);
  u16x4 o;
#pragma unroll
  for (int j = 0; j < 4; ++j) o[j] = f2bf((v[j] - mean) * rstd * wv4[j] + bv4[j]);
  *(u16x4*)(out + (size_t)row * 768 + t * 4) = o;
}

// ---------------------------------------------------------------------------
// GEMM: C[M][N] = A[M][K](bf16) * BT[N][K](bf16)^T + bias (+epilogue)
// 128x128 tile, BK=32, 4 waves, m97 structure w/ global_load_lds(16B).
// ---------------------------------------------------------------------------
#define EPI_QKV 0    // bf16 out = val
#define EPI_RESID 1  // f32  out = val + resid
#define EPI_GELU 2   // bf16 out = gelu(val)

template <int EPI>
__global__ __launch_bounds__(256) void k_gemm(const u16* __restrict__ A,
                                              const u16* __restrict__ BT,
                                              const float* __restrict__ bias,
                                              const float* __restrict__ resid,
                                              void* __restrict__ outp,
                                              int M, int N, int K) {
  __shared__ u16 As[128 * 32];
  __shared__ u16 Bs[128 * 32];
  const int t = threadIdx.x;
  const int lane = t & 63, w = t >> 6;
  const int l15 = lane & 15, l4 = lane >> 4;
  const int wr = w >> 1, wc = w & 1;
  const int m0 = blockIdx.y * 128, n0 = blockIdx.x * 128;

  f32x4 acc[4][4] = {};

  for (int kt = 0; kt < K; kt += 32) {
#pragma unroll
    for (int i = 0; i < 2; ++i) {
      int c = w * 128 + i * 64 + lane;       // 16B chunk id, 0..511
      int m = c >> 2, k16 = (c & 3) * 8;
      gload_lds16(A + (size_t)(m0 + m) * K + kt + k16, As + c * 8);
    }
#pragma unroll
    for (int i = 0; i < 2; ++i) {
      int c = w * 128 + i * 64 + lane;
      int n = c >> 2, k16 = (c & 3) * 8;
      gload_lds16(BT + (size_t)(n0 + n) * K + kt + k16, Bs + c * 8);
    }
    __syncthreads();
    bf16x8 af[4], bfr[4];
#pragma unroll
    for (int f = 0; f < 4; ++f)
      af[f] = *(const bf16x8*)(As + (wr * 64 + f * 16 + l15) * 32 + l4 * 8);
#pragma unroll
    for (int f = 0; f < 4; ++f)
      bfr[f] = *(const bf16x8*)(Bs + (wc * 64 + f * 16 + l15) * 32 + l4 * 8);
#pragma unroll
    for (int fi = 0; fi < 4; ++fi)
#pragma unroll
      for (int fj = 0; fj < 4; ++fj)
        acc[fi][fj] = __builtin_amdgcn_mfma_f32_16x16x32_bf16(af[fi], bfr[fj], acc[fi][fj], 0, 0, 0);
    __syncthreads();
  }

#pragma unroll
  for (int fi = 0; fi < 4; ++fi) {
    const int mbase = m0 + wr * 64 + fi * 16 + l4 * 4;
#pragma unroll
    for (int fj = 0; fj < 4; ++fj) {
      const int n = n0 + wc * 64 + fj * 16 + l15;
      const float bn = bias[n];
#pragma unroll
      for (int r = 0; r < 4; ++r) {
        const size_t idx = (size_t)(mbase + r) * N + n;
        float val = acc[fi][fj][r] + bn;
        if constexpr (EPI == EPI_QKV) {
          ((u16*)outp)[idx] = f2bf(val);
        } else if constexpr (EPI == EPI_RESID) {
          ((float*)outp)[idx] = val + resid[idx];
        } else {
          // gelu(v) = v * sigmoid(2z), z = 0.79788456*(v + 0.044715 v^3) — exact identity
          float z2 = 1.5957691216057308f * (val + 0.044715f * val * val * val);
          float g = val / (1.0f + exp2f(-1.4426950408889634f * z2));
          ((u16*)outp)[idx] = f2bf(g);
        }
      }
    }
  }
}

// ---------------------------------------------------------------------------
// Causal flash attention, SWAPPED-QK^T, QBLK=128, 8 waves, double-buffered
// global_load_lds staging (1 barrier/tile), XOR-swizzled K/V LDS, LPT order,
// setprio around MFMA clusters.
// grid (S/128, H, B), 512 thr.  Wave w owns q rows q0+16w .. q0+16w+15.
// K/V tiles [64][64] linear LDS; LDS[r][c16] holds global chunk c16^(r&7)
// (both-sides swizzle: pre-swizzled global source + swizzled ds_read).
// ---------------------------------------------------------------------------
__global__ __launch_bounds__(512) void k_attn(const u16* __restrict__ qkv,
                                              const u16* __restrict__ vt,
                                              u16* __restrict__ out) {
  __shared__ u16 Ks[2][64 * 64];
  __shared__ u16 Vs[2][64 * 64];
  __shared__ u16 Ps[8][16 * 72];
  const int t = threadIdx.x, lane = t & 63, w = t >> 6;   // w 0..7
  const int l15 = lane & 15, l4 = lane >> 4;
  const int l44 = l4 * 4;
  const int qb = (int)gridDim.x - 1 - (int)blockIdx.x;    // LPT: longest first
  const int h = blockIdx.y, b = blockIdx.z;
  const int q0 = qb * 128;
  const int qw = q0 + w * 16;              // wave's first q row
  const u16* qbase = qkv + (size_t)b * 2048 * 2304 + h * 64;
  const u16* kbase = qbase + 768;
  const u16* vtb = vt + ((size_t)(b * 12 + h) * 64) * 2048;

  // staging: thread t owns LDS bytes [t*16, t*16+16) = row t>>3, chunk t&7.
  // source chunk is XOR-swizzled so reads can apply the same XOR.
  const int sr = t >> 3;
  const int scx = (t & 7) ^ (sr & 7);
  const size_t kgo = (size_t)sr * 2304 + scx * 8;   // + kv0*2304
  const size_t vgo = (size_t)sr * 2048 + scx * 8;   // + kv0

  // read-side swizzled chunk offsets (elements): row&7 == l15&7 for all frags
  const int rx0 = ((l4 ^ (l15 & 7)) * 8);
  const int rx1 = (((4 + l4) ^ (l15 & 7)) * 8);

  // Q fragment (B-operand rows = q), prescaled by 1/sqrt(64) * log2(e)
  const int qrow = qw + l15;
  bf16x8 qf0, qf1;
  {
    const float PRE = 0.18033688011112042f;  // 0.125 * log2(e)
    u16x8 r0 = *(const u16x8*)(qbase + (size_t)qrow * 2304 + l4 * 8);
    u16x8 r1 = *(const u16x8*)(qbase + (size_t)qrow * 2304 + 32 + l4 * 8);
    u16x8 s0, s1;
#pragma unroll
    for (int j = 0; j < 8; ++j) { s0[j] = f2bf(bf2f(r0[j]) * PRE); s1[j] = f2bf(bf2f(r1[j]) * PRE); }
    qf0 = *(bf16x8*)&s0;
    qf1 = *(bf16x8*)&s1;
  }

  float m_run = -1e30f, l_run = 0.f;
  f32x4 o_acc[4] = {};
  u16* pw = &Ps[w][0];
  const int qq = qw + l15;                 // global q row (causal mask)

  const int ntiles = 2 * qb + 2;           // kv0 = 0 .. (2qb+1)*64

  // prologue: stage tile 0 into buf 0
  gload_lds16(kbase + kgo, (char*)&Ks[0][0] + t * 16);
  gload_lds16(vtb + vgo, (char*)&Vs[0][0] + t * 16);

  for (int kt = 0; kt < ntiles; ++kt) {
    __syncthreads();                       // drains vmcnt: buf (kt&1) ready
    if (kt + 1 < ntiles) {                 // prefetch next tile (flies under compute)
      const int nb = (kt + 1) & 1;
      gload_lds16(kbase + (size_t)(kt + 1) * 64 * 2304 + kgo, (char*)&Ks[nb][0] + t * 16);
      gload_lds16(vtb + (size_t)(kt + 1) * 64 + vgo, (char*)&Vs[nb][0] + t * 16);
    }
    const int kv0 = kt * 64;
    if (kv0 <= qw + 15) {                  // wave has live rows in this tile
      const u16* kb = &Ks[kt & 1][0];
      const u16* vb = &Vs[kt & 1][0];
      // S^T = K * Q^T  (A = K rows->k, B = Q rows->q)
      f32x4 sa[4] = {};
      __builtin_amdgcn_s_setprio(1);
#pragma unroll
      for (int c = 0; c < 4; ++c) {
        bf16x8 kf0 = *(const bf16x8*)(kb + (c * 16 + l15) * 64 + rx0);
        bf16x8 kf1 = *(const bf16x8*)(kb + (c * 16 + l15) * 64 + rx1);
        sa[c] = __builtin_amdgcn_mfma_f32_16x16x32_bf16(kf0, qf0, sa[c], 0, 0, 0);
        sa[c] = __builtin_amdgcn_mfma_f32_16x16x32_bf16(kf1, qf1, sa[c], 0, 0, 0);
      }
      __builtin_amdgcn_s_setprio(0);

      if (kv0 + 63 > qw) {                 // wave-uniform: partial (diagonal) tile
#pragma unroll
        for (int c = 0; c < 4; ++c)
#pragma unroll
          for (int r = 0; r < 4; ++r)
            if (kv0 + c * 16 + l44 + r > qq) sa[c][r] = -1e30f;
      }

      // row max (row = q = l15): in-lane over 16, then cross-l4
      float pm = fmaxf(fmaxf(sa[0][0], sa[0][1]), fmaxf(sa[0][2], sa[0][3]));
#pragma unroll
      for (int c = 1; c < 4; ++c)
        pm = fmaxf(pm, fmaxf(fmaxf(sa[c][0], sa[c][1]), fmaxf(sa[c][2], sa[c][3])));
      pm = fmaxf(pm, __shfl_xor(pm, 16));
      pm = fmaxf(pm, __shfl_xor(pm, 32));

      // defer-max rescale (log2-domain threshold 8 -> P bounded by 256)
      if (__any(pm > m_run + 8.0f)) {
        float mn = fmaxf(m_run, pm);
        float scq = exp2f(m_run - mn);
        m_run = mn;
        l_run *= scq;
#pragma unroll
        for (int r = 0; r < 4; ++r) {
          float s = __shfl(scq, l44 + r);  // o rows are q = 4*l4 + r
#pragma unroll
          for (int cd = 0; cd < 4; ++cd) o_acc[cd][r] *= s;
        }
      }

      // P = exp2(S - m), row-sum, pack to bf16
      float ls = 0.f;
      u16x4 pk[4];
#pragma unroll
      for (int c = 0; c < 4; ++c)
#pragma unroll
        for (int r = 0; r < 4; ++r) {
          float p = exp2f(sa[c][r] - m_run);
          ls += p;
          pk[c][r] = f2bf(p);
        }
      ls += __shfl_xor(ls, 16);
      ls += __shfl_xor(ls, 32);
      l_run += ls;

      // store P row-major [q=16][72]: lane writes 4 consecutive k per c (b64)
#pragma unroll
      for (int c = 0; c < 4; ++c)
        *(u16x4*)(pw + l15 * 72 + c * 16 + l44) = pk[c];

      bf16x8 pa0 = *(const bf16x8*)(pw + l15 * 72 + l4 * 8);
      bf16x8 pa1 = *(const bf16x8*)(pw + l15 * 72 + 32 + l4 * 8);

      __builtin_amdgcn_s_setprio(1);
#pragma unroll
      for (int cd = 0; cd < 4; ++cd) {
        bf16x8 vf0 = *(const bf16x8*)(vb + (cd * 16 + l15) * 64 + rx0);
        bf16x8 vf1 = *(const bf16x8*)(vb + (cd * 16 + l15) * 64 + rx1);
        o_acc[cd] = __builtin_amdgcn_mfma_f32_16x16x32_bf16(pa0, vf0, o_acc[cd], 0, 0, 0);
        o_acc[cd] = __builtin_amdgcn_mfma_f32_16x16x32_bf16(pa1, vf1, o_acc[cd], 0, 0, 0);
      }
      __builtin_amdgcn_s_setprio(0);
    }
  }

  // epilogue: O rows q = qw + 4*l4 + r; cols d = cd*16 + l15
  float lr[4];
#pragma unroll
  for (int r = 0; r < 4; ++r) lr[r] = 1.0f / __shfl(l_run, l44 + r);
#pragma unroll
  for (int cd = 0; cd < 4; ++cd)
#pragma unroll
    for (int r = 0; r < 4; ++r) {
      int qr = qw + l44 + r;
      out[((size_t)(b * 2048) + qr) * 768 + h * 64 + cd * 16 + l15] = f2bf(o_acc[cd][r] * lr[r]);
    }
}

// ---------------------------------------------------------------------------
extern "C" void kernel_launch(void* const* d_in, const int* in_sizes, int n_in,
                              void* d_out, int out_size, void* d_ws, size_t ws_size,
                              hipStream_t stream) {
  (void)in_sizes; (void)n_in; (void)out_size; (void)ws_size;
  const float* x      = (const float*)d_in[0];
  const float* ln1_w  = (const float*)d_in[1];
  const float* ln1_b  = (const float*)d_in[2];
  const float* w_attn = (const float*)d_in[3];
  const float* b_attn = (const float*)d_in[4];
  const float* w_proj = (const float*)d_in[5];
  const float* b_proj = (const float*)d_in[6];
  const float* ln2_w  = (const float*)d_in[7];
  const float* ln2_b  = (const float*)d_in[8];
  const float* w_fc   = (const float*)d_in[9];
  const float* b_fc   = (const float*)d_in[10];
  const float* w_fcp  = (const float*)d_in[11];
  const float* b_fcp  = (const float*)d_in[12];
  float* out = (float*)d_out;

  char* ws = (char*)d_ws;
  // workspace layout (bytes)
  u16*   wt_attn = (u16*)(ws + 0);                      //  [2304][768]  3,538,944
  u16*   wt_proj = (u16*)(ws + 3538944);                //  [768][768]   1,179,648
  u16*   wt_fc   = (u16*)(ws + 4718592);                //  [3072][768]  4,718,592
  u16*   wt_fcp  = (u16*)(ws + 9437184);                //  [768][3072]  4,718,592
  u16*   h_ln    = (u16*)(ws + 14155776);               //  [8192][768] 12,582,912
  u16*   qkv     = (u16*)(ws + 26738688);               //  [8192][2304] 37,748,736
  u16*   vtb     = (u16*)(ws + 64487424);               //  [48][64][2048] 12,582,912
  u16*   h_gelu  = qkv;                                 //  [8192][3072] aliases qkv+vt
  u16*   attn    = (u16*)(ws + 77070336);               //  [8192][768] 12,582,912
  float* x2      = (float*)(ws + 89653248);             //  [8192][768] 25,165,824
  // total 114,819,072 bytes

  // 1) weight transpose + bf16 cast
  k_transpose_w<<<dim3(36, 12), 256, 0, stream>>>(w_attn, wt_attn, 768, 2304);
  k_transpose_w<<<dim3(12, 12), 256, 0, stream>>>(w_proj, wt_proj, 768, 768);
  k_transpose_w<<<dim3(48, 12), 256, 0, stream>>>(w_fc, wt_fc, 768, 3072);
  k_transpose_w<<<dim3(12, 48), 256, 0, stream>>>(w_fcp, wt_fcp, 3072, 768);
  // 2) LN1
  k_layernorm<<<8192, 192, 0, stream>>>(x, ln1_w, ln1_b, h_ln);
  // 3) QKV GEMM
  k_gemm<EPI_QKV><<<dim3(18, 64), 256, 0, stream>>>(h_ln, wt_attn, b_attn, nullptr, qkv, 8192, 2304, 768);
  // 4) V transpose
  k_transpose_v<<<dim3(32, 48), 256, 0, stream>>>(qkv, vtb);
  // 5) attention (QBLK=128, 8 waves, dbuf staging, LPT)
  k_attn<<<dim3(16, 12, 4), 512, 0, stream>>>(qkv, vtb, attn);
  // 6) out-proj GEMM + residual -> x2 (fp32)
  k_gemm<EPI_RESID><<<dim3(6, 64), 256, 0, stream>>>(attn, wt_proj, b_proj, x, x2, 8192, 768, 768);
  // 7) LN2
  k_layernorm<<<8192, 192, 0, stream>>>(x2, ln2_w, ln2_b, h_ln);
  // 8) FC GEMM + GELU
  k_gemm<EPI_GELU><<<dim3(24, 64), 256, 0, stream>>>(h_ln, wt_fc, b_fc, nullptr, h_gelu, 8192, 3072, 768);
  // 9) FC-proj GEMM + residual -> out (fp32)
  k_gemm<EPI_RESID><<<dim3(6, 64), 256, 0, stream>>>(h_gelu, wt_fcp, b_fcp, x2, out, 8192, 768, 3072);
}